// Round 2
// baseline (2520.006 us; speedup 1.0000x reference)
//
#include <hip/hip_runtime.h>
#include <hip/hip_bf16.h>

#define GN 200000
#define GB 10000
#define GE 600000
// IN=2, C1=128, C2=256; NL1=256, NL2=512, OUT=2; EL1=256, EL2=512, EOUT=1

// ---------------- conv layer 1: g1 = lrelu(x@W1r.T + msg1@W1n.T + b1) ----------------
// writes gm[n*256 + c] (c<128) and zeros gm[n*256 + 128 + c] (msg2 half)
__global__ void conv1_kernel(const float* __restrict__ x, const float* __restrict__ msg1,
                             const float* __restrict__ W1r, const float* __restrict__ W1n,
                             const float* __restrict__ b1, float* __restrict__ gm) {
    int idx = blockIdx.x * 256 + threadIdx.x;   // n*128 + c, total GN*128 (exact multiple of 256)
    int n = idx >> 7, c = idx & 127;
    float x0 = x[n * 2], x1 = x[n * 2 + 1];
    float m0 = msg1[n * 2], m1 = msg1[n * 2 + 1];
    float v = b1[c];
    v = fmaf(x0, W1r[c * 2], v);
    v = fmaf(x1, W1r[c * 2 + 1], v);
    v = fmaf(m0, W1n[c * 2], v);
    v = fmaf(m1, W1n[c * 2 + 1], v);
    v = v >= 0.f ? v : 0.01f * v;
    gm[(size_t)n * 256 + c] = v;
    gm[(size_t)n * 256 + 128 + c] = 0.f;   // zero msg2 half for scatter2
}

// ---------------- edge scatter, layer 1 (width 2) ----------------
__global__ void scatter1_kernel(const float* __restrict__ x, const int* __restrict__ src,
                                const int* __restrict__ dst, float* __restrict__ msg1) {
    int e = blockIdx.x * 256 + threadIdx.x;
    if (e >= GE) return;
    int s = src[e], d = dst[e];
    atomicAdd(&msg1[d * 2], x[s * 2]);
    atomicAdd(&msg1[d * 2 + 1], x[s * 2 + 1]);
}

// ---------------- edge scatter, layer 2 (width 128) ----------------
// reads g1 = gm[:,0:128], atomically accumulates into gm[:,128:256]
__global__ void scatter2_kernel(const float* __restrict__ gm, const int* __restrict__ src,
                                const int* __restrict__ dst, float* __restrict__ gmw) {
    int idx = blockIdx.x * 256 + threadIdx.x;   // e*128 + c, total GE*128 = 76.8M (exact)
    int e = idx >> 7, c = idx & 127;
    int s = src[e], d = dst[e];
    atomicAdd(&gmw[(size_t)d * 256 + 128 + c], gm[(size_t)s * 256 + c]);
}

// ---------------- generic fp32 GEMM: act(A @ W.T + bias) ----------------
// A: [M][lda] row-major (cols 0..K), W: [Nout][K] row-major.
// MODE 0: out[m*ldo + bn+n] = v                        (plain)
// MODE 1: atomicAdd(&out[aux[m]*ldo + bn+n], v)        (fused segment-sum readout, aux=batch sorted)
// MODE 2: indirect A row: asrc = m<GB ? aux[m] : aux2[m-GB]; write use-style:
//         orow = m<GB ? m : m-GB; ocol = m<GB ? 256 : 512; out[orow*ldo + ocol + bn+n] = v
// ACT: 0=none, 1=leaky_relu(0.01), 2=tanh
template <int ACT, int MODE>
__global__ void gemm_act_kernel(const float* __restrict__ A, int lda,
                                const float* __restrict__ W,
                                const float* __restrict__ bias,
                                float* __restrict__ out, int ldo,
                                int M, int K, int ntiles,
                                const int* __restrict__ aux,
                                const int* __restrict__ aux2) {
    __shared__ float As[16][68];
    __shared__ float Ws[16][68];
    int bm = (blockIdx.x / ntiles) * 64;
    int bn = (blockIdx.x % ntiles) * 64;
    int tid = threadIdx.x;
    int r  = tid >> 2;          // 0..63
    int k4 = (tid & 3) * 4;     // 0,4,8,12
    int mi = (tid & 15) * 4;
    int ni = (tid >> 4) * 4;
    int arow = bm + r;
    int asrc = arow;
    if (MODE == 2) asrc = (arow < M) ? (arow < GB ? aux[arow] : aux2[arow - GB]) : 0;
    float acc[4][4] = {{0.f}};
    for (int k0 = 0; k0 < K; k0 += 16) {
        float4 av = make_float4(0.f, 0.f, 0.f, 0.f);
        if (arow < M) av = *(const float4*)&A[(size_t)asrc * lda + k0 + k4];
        float4 wv = *(const float4*)&W[(size_t)(bn + r) * K + k0 + k4];
        __syncthreads();
        As[k4 + 0][r] = av.x; As[k4 + 1][r] = av.y; As[k4 + 2][r] = av.z; As[k4 + 3][r] = av.w;
        Ws[k4 + 0][r] = wv.x; Ws[k4 + 1][r] = wv.y; Ws[k4 + 2][r] = wv.z; Ws[k4 + 3][r] = wv.w;
        __syncthreads();
#pragma unroll
        for (int k = 0; k < 16; ++k) {
            float4 a = *(const float4*)&As[k][mi];
            float4 w = *(const float4*)&Ws[k][ni];
            acc[0][0] = fmaf(a.x, w.x, acc[0][0]);
            acc[0][1] = fmaf(a.x, w.y, acc[0][1]);
            acc[0][2] = fmaf(a.x, w.z, acc[0][2]);
            acc[0][3] = fmaf(a.x, w.w, acc[0][3]);
            acc[1][0] = fmaf(a.y, w.x, acc[1][0]);
            acc[1][1] = fmaf(a.y, w.y, acc[1][1]);
            acc[1][2] = fmaf(a.y, w.z, acc[1][2]);
            acc[1][3] = fmaf(a.y, w.w, acc[1][3]);
            acc[2][0] = fmaf(a.z, w.x, acc[2][0]);
            acc[2][1] = fmaf(a.z, w.y, acc[2][1]);
            acc[2][2] = fmaf(a.z, w.z, acc[2][2]);
            acc[2][3] = fmaf(a.z, w.w, acc[2][3]);
            acc[3][0] = fmaf(a.w, w.x, acc[3][0]);
            acc[3][1] = fmaf(a.w, w.y, acc[3][1]);
            acc[3][2] = fmaf(a.w, w.z, acc[3][2]);
            acc[3][3] = fmaf(a.w, w.w, acc[3][3]);
        }
    }
    // epilogue
    if (MODE == 1) {
        // run-length compressed atomic readout (batch sorted -> consecutive rows often同batch)
        float s0 = 0.f, s1 = 0.f, s2 = 0.f, s3 = 0.f;
        int cur = -1;
#pragma unroll
        for (int i = 0; i < 4; ++i) {
            int m = bm + mi + i;
            if (m >= M) break;
            float v[4];
#pragma unroll
            for (int j = 0; j < 4; ++j) {
                float t = acc[i][j] + bias[bn + ni + j];
                if (ACT == 1) t = t >= 0.f ? t : 0.01f * t;
                if (ACT == 2) t = tanhf(t);
                v[j] = t;
            }
            int b = aux[m];
            if (b != cur) {
                if (cur >= 0) {
                    atomicAdd(&out[(size_t)cur * ldo + bn + ni + 0], s0);
                    atomicAdd(&out[(size_t)cur * ldo + bn + ni + 1], s1);
                    atomicAdd(&out[(size_t)cur * ldo + bn + ni + 2], s2);
                    atomicAdd(&out[(size_t)cur * ldo + bn + ni + 3], s3);
                }
                cur = b; s0 = v[0]; s1 = v[1]; s2 = v[2]; s3 = v[3];
            } else {
                s0 += v[0]; s1 += v[1]; s2 += v[2]; s3 += v[3];
            }
        }
        if (cur >= 0) {
            atomicAdd(&out[(size_t)cur * ldo + bn + ni + 0], s0);
            atomicAdd(&out[(size_t)cur * ldo + bn + ni + 1], s1);
            atomicAdd(&out[(size_t)cur * ldo + bn + ni + 2], s2);
            atomicAdd(&out[(size_t)cur * ldo + bn + ni + 3], s3);
        }
    } else {
#pragma unroll
        for (int i = 0; i < 4; ++i) {
            int m = bm + mi + i;
            if (m >= M) break;
            size_t obase;
            if (MODE == 2) {
                int orow = (m < GB) ? m : m - GB;
                int ocol = (m < GB) ? 256 : 512;
                obase = (size_t)orow * ldo + ocol;
            } else {
                obase = (size_t)m * ldo;
            }
#pragma unroll
            for (int j = 0; j < 4; ++j) {
                float v = acc[i][j] + bias[bn + ni + j];
                if (ACT == 1) v = v >= 0.f ? v : 0.01f * v;
                if (ACT == 2) v = tanhf(v);
                out[obase + bn + ni + j] = v;
            }
        }
    }
}

// ---------------- Wcat[c][k] = k<128 ? W2r[c][k] : W2n[c][k-128] ----------------
__global__ void prep_wcat_kernel(const float* __restrict__ W2r, const float* __restrict__ W2n,
                                 float* __restrict__ Wcat) {
    int idx = blockIdx.x * 256 + threadIdx.x;   // c*256 + k, total 65536
    int c = idx >> 8, k = idx & 255;
    Wcat[idx] = (k < 128) ? W2r[c * 128 + k] : W2n[c * 128 + (k - 128)];
}

// ---------------- output head: yp = h @ W3.T + b3 (nout = 4 or 2, K = 512) ----------------
__global__ void outhead_kernel(const float* __restrict__ h, const float* __restrict__ W,
                               const float* __restrict__ bias, float* __restrict__ yp, int nout) {
    int idx = blockIdx.x * 256 + threadIdx.x;
    if (idx >= GB * nout) return;
    int b = idx / nout, o = idx - b * nout;
    const float4* hr = (const float4*)(h + (size_t)b * 512);
    const float4* wr = (const float4*)(W + (size_t)o * 512);
    float s = 0.f;
#pragma unroll 4
    for (int k = 0; k < 128; ++k) {
        float4 hv = hr[k], wv = wr[k];
        s = fmaf(hv.x, wv.x, s);
        s = fmaf(hv.y, wv.y, s);
        s = fmaf(hv.z, wv.z, s);
        s = fmaf(hv.w, wv.w, s);
    }
    yp[b * nout + o] = s + bias[o];
}

// ---------------- losses ----------------
__global__ void loss_kernel(const float* __restrict__ ypx, const float* __restrict__ ypA,
                            const float* __restrict__ y_x, const float* __restrict__ y_A,
                            float* __restrict__ out) {
    int b = blockIdx.x * 256 + threadIdx.x;
    if (b >= GB) return;
#pragma unroll
    for (int j = 0; j < 2; ++j) {
        float p  = ypx[b * 4 + j];
        float a  = p * p + 1e-7f;
        float mu = ypx[b * 4 + 2 + j];
        float e  = (y_x[b * 2 + j] - mu) / a;
        out[b * 2 + j] = e * e + logf(a);
    }
    float p  = ypA[b * 2 + 0];
    float a  = p * p + 1e-7f;
    float mu = ypA[b * 2 + 1];
    float e  = (y_A[b] - mu) / a;
    out[2 * GB + b] = e * e + logf(a);
}

extern "C" void kernel_launch(void* const* d_in, const int* in_sizes, int n_in,
                              void* d_out, int out_size, void* d_ws, size_t ws_size,
                              hipStream_t stream) {
    const float* x_x     = (const float*)d_in[0];
    const float* y_x     = (const float*)d_in[1];
    const int*   ei_x    = (const int*)d_in[2];
    const int*   batch_x = (const int*)d_in[3];
    const float* x_A     = (const float*)d_in[4];
    const float* y_A     = (const float*)d_in[5];
    const int*   ei_A    = (const int*)d_in[6];
    const int*   batch_A = (const int*)d_in[7];
    const int*   idi_A   = (const int*)d_in[8];
    const int*   idj_A   = (const int*)d_in[9];
    const float* W1r = (const float*)d_in[10];
    const float* W1n = (const float*)d_in[11];
    const float* b1  = (const float*)d_in[12];
    const float* W2r = (const float*)d_in[13];
    const float* W2n = (const float*)d_in[14];
    const float* b2  = (const float*)d_in[15];
    const float* nW1 = (const float*)d_in[16];
    const float* nb1 = (const float*)d_in[17];
    const float* nW2 = (const float*)d_in[18];
    const float* nb2 = (const float*)d_in[19];
    const float* nW3 = (const float*)d_in[20];
    const float* nb3 = (const float*)d_in[21];
    const float* eW1 = (const float*)d_in[22];
    const float* eb1 = (const float*)d_in[23];
    const float* eW2 = (const float*)d_in[24];
    const float* eb2 = (const float*)d_in[25];
    const float* eW3 = (const float*)d_in[26];
    const float* eb3 = (const float*)d_in[27];

    // ---- workspace layout (floats): total 61,905,536 = 236.2 MiB ----
    float* ws = (float*)d_ws;
    float* gm   = ws;                       // 51,200,000  [g1 | msg2] interleaved, N x 256
    float* msg1 = gm   + (size_t)GN * 256;  //    400,000
    float* rgx  = msg1 + (size_t)GN * 2;    //  2,560,000  read_g_x
    float* use  = rgx  + (size_t)GB * 256;  //  7,680,000  [read_g_A | g_A[idi] | g_A[idj]]
    float* wcat = use  + (size_t)GB * 768;  //     65,536
    // aliases into gm (gm dead after the sel-GEMM, before MLPs start):
    float* h1   = gm;                       //  2,560,000
    float* h2   = h1 + (size_t)GB * 256;    //  5,120,000
    float* ypx  = h2 + (size_t)GB * 512;    //     40,000
    float* ypA  = ypx + (size_t)GB * 4;     //     20,000

    size_t need = ((size_t)GN * 256 + (size_t)GN * 2 + (size_t)GB * 256 +
                   (size_t)GB * 768 + 65536) * sizeof(float);
    if (ws_size < need) return;  // fail validation cleanly -> diagnoses ws_size bound

    float* out = (float*)d_out;

    prep_wcat_kernel<<<256, 256, 0, stream>>>(W2r, W2n, wcat);

    const int conv2_grid = (GN / 64) * 4;             // 12500
    const int mlp_mt = (GB + 63) / 64;                // 157
    const int sel_grid = ((2 * GB + 63) / 64) * 4;    // 313*4 = 1252

    for (int g = 0; g < 2; ++g) {
        const float* x   = g == 0 ? x_x : x_A;
        const int*   src = (g == 0 ? ei_x : ei_A);
        const int*   dst = src + GE;
        const int*   bat = g == 0 ? batch_x : batch_A;

        hipMemsetAsync(msg1, 0, (size_t)GN * 2 * sizeof(float), stream);
        scatter1_kernel<<<(GE + 255) / 256, 256, 0, stream>>>(x, src, dst, msg1);
        conv1_kernel<<<GN * 128 / 256, 256, 0, stream>>>(x, msg1, W1r, W1n, b1, gm);
        scatter2_kernel<<<GE * 128 / 256, 256, 0, stream>>>(gm, src, dst, gm);

        if (g == 0) {
            hipMemsetAsync(rgx, 0, (size_t)GB * 256 * sizeof(float), stream);
            gemm_act_kernel<1, 1><<<conv2_grid, 256, 0, stream>>>(
                gm, 256, wcat, b2, rgx, 256, GN, 256, 4, bat, nullptr);
        } else {
            hipMemsetAsync(use, 0, (size_t)GB * 768 * sizeof(float), stream);
            gemm_act_kernel<1, 1><<<conv2_grid, 256, 0, stream>>>(
                gm, 256, wcat, b2, use, 768, GN, 256, 4, bat, nullptr);
            // recompute selected rows g_A[idi], g_A[idj] -> use[:,256:768]
            gemm_act_kernel<1, 2><<<sel_grid, 256, 0, stream>>>(
                gm, 256, wcat, b2, use, 768, 2 * GB, 256, 4, idi_A, idj_A);
        }
    }

    // node MLP (h1/h2 alias gm; gm is dead now)
    gemm_act_kernel<2, 0><<<mlp_mt * 4, 256, 0, stream>>>(rgx, 256, nW1, nb1, h1, 256, GB, 256, 4, nullptr, nullptr);
    gemm_act_kernel<2, 0><<<mlp_mt * 8, 256, 0, stream>>>(h1, 256, nW2, nb2, h2, 512, GB, 256, 8, nullptr, nullptr);
    outhead_kernel<<<(GB * 4 + 255) / 256, 256, 0, stream>>>(h2, nW3, nb3, ypx, 4);

    // edge MLP (reuses h1/h2)
    gemm_act_kernel<2, 0><<<mlp_mt * 4, 256, 0, stream>>>(use, 768, eW1, eb1, h1, 256, GB, 768, 4, nullptr, nullptr);
    gemm_act_kernel<2, 0><<<mlp_mt * 8, 256, 0, stream>>>(h1, 256, eW2, eb2, h2, 512, GB, 256, 8, nullptr, nullptr);
    outhead_kernel<<<(GB * 2 + 255) / 256, 256, 0, stream>>>(h2, eW3, eb3, ypA, 2);

    loss_kernel<<<(GB + 255) / 256, 256, 0, stream>>>(ypx, ypA, y_x, y_A, out);
}

// Round 3
// 1350.484 us; speedup vs baseline: 1.8660x; 1.8660x over previous
//
#include <hip/hip_runtime.h>
#include <hip/hip_bf16.h>

#define GN 200000
#define GB 10000
#define GE 600000
// IN=2, C1=128, C2=256; NL1=256, NL2=512, OUT=2; EL1=256, EL2=512, EOUT=1

typedef __bf16 bf16x8 __attribute__((ext_vector_type(8)));
typedef float  f32x4  __attribute__((ext_vector_type(4)));

// ---------------- conv layer 1 ----------------
__global__ void conv1_kernel(const float* __restrict__ x, const float* __restrict__ msg1,
                             const float* __restrict__ W1r, const float* __restrict__ W1n,
                             const float* __restrict__ b1, float* __restrict__ gm) {
    int idx = blockIdx.x * 256 + threadIdx.x;   // n*128 + c
    int n = idx >> 7, c = idx & 127;
    float x0 = x[n * 2], x1 = x[n * 2 + 1];
    float m0 = msg1[n * 2], m1 = msg1[n * 2 + 1];
    float v = b1[c];
    v = fmaf(x0, W1r[c * 2], v);
    v = fmaf(x1, W1r[c * 2 + 1], v);
    v = fmaf(m0, W1n[c * 2], v);
    v = fmaf(m1, W1n[c * 2 + 1], v);
    v = v >= 0.f ? v : 0.01f * v;
    gm[(size_t)n * 256 + c] = v;
    gm[(size_t)n * 256 + 128 + c] = 0.f;
}

// ---------------- edge scatters ----------------
__global__ void scatter1_kernel(const float* __restrict__ x, const int* __restrict__ src,
                                const int* __restrict__ dst, float* __restrict__ msg1) {
    int e = blockIdx.x * 256 + threadIdx.x;
    if (e >= GE) return;
    int s = src[e], d = dst[e];
    atomicAdd(&msg1[d * 2], x[s * 2]);
    atomicAdd(&msg1[d * 2 + 1], x[s * 2 + 1]);
}

__global__ void scatter2_kernel(const float* __restrict__ gm, const int* __restrict__ src,
                                const int* __restrict__ dst, float* __restrict__ gmw) {
    int idx = blockIdx.x * 256 + threadIdx.x;   // e*128 + c
    int e = idx >> 7, c = idx & 127;
    int s = src[e], d = dst[e];
    atomicAdd(&gmw[(size_t)d * 256 + 128 + c], gm[(size_t)s * 256 + c]);
}

// ---------------- weight prep: fp32 -> bf16 hi/lo ----------------
__global__ void prep_wcat_split(const float* __restrict__ W2r, const float* __restrict__ W2n,
                                __bf16* __restrict__ hi, __bf16* __restrict__ lo) {
    int idx = blockIdx.x * 256 + threadIdx.x;   // c*256 + k, total 65536
    int c = idx >> 8, k = idx & 255;
    float v = (k < 128) ? W2r[c * 128 + k] : W2n[c * 128 + (k - 128)];
    __bf16 h = (__bf16)v;
    hi[idx] = h;
    lo[idx] = (__bf16)(v - (float)h);
}

__global__ void prep_split(const float* __restrict__ W, __bf16* __restrict__ hi,
                           __bf16* __restrict__ lo, int n) {
    int i = blockIdx.x * 256 + threadIdx.x;
    if (i >= n) return;
    float v = W[i];
    __bf16 h = (__bf16)v;
    hi[i] = h;
    lo[i] = (__bf16)(v - (float)h);
}

// ---------------- MFMA split-bf16 GEMM: act(A @ W.T + bias) ----------------
// A: fp32 [M][lda] (cols 0..K), W pre-split bf16 hi/lo [Ncols][K]. BM=64, BN=256, KS=32.
// 4 waves/block, wave w computes rows 0..63 x cols [64w,64w+64).
// MODE 0: out[m*ldo + bn+n] = v
// MODE 1: RLE + atomicAdd(&out[aux[m]*ldo + bn+n], v)   (aux = sorted batch)
// MODE 2: A-row indirect (aux/aux2), write use-style at col offset 256/512
// ACT: 1=leaky_relu(0.01), 2=tanh
template <int ACT, int MODE>
__global__ __launch_bounds__(256, 2)
void mfma_gemm_kernel(const float* __restrict__ A, int lda,
                      const __bf16* __restrict__ whi, const __bf16* __restrict__ wlo,
                      const float* __restrict__ bias,
                      float* __restrict__ out, int ldo,
                      int M, int K, int ctiles,
                      const int* __restrict__ aux, const int* __restrict__ aux2) {
    __shared__ __bf16 Ah[64][40], Al[64][40], Bh[256][40], Bl[256][40];
    const int bm = (blockIdx.x / ctiles) * 64;
    const int bn = (blockIdx.x % ctiles) * 256;
    const int tid = threadIdx.x, lane = tid & 63, wv = tid >> 6;

    // staging roles
    const int sar = tid >> 2;            // A row 0..63
    const int sak = (tid & 3) * 8;       // A k-offset 0,8,16,24
    const int arow = bm + sar;
    long asrc = arow;
    if (MODE == 2) asrc = (arow < M) ? (arow < GB ? aux[arow] : aux2[arow - GB]) : 0;
    const bool aval = (arow < M);
    const float* Arow = A + (size_t)asrc * lda;
    const __bf16* Wrh = whi + (size_t)(bn + tid) * K;
    const __bf16* Wrl = wlo + (size_t)(bn + tid) * K;

    f32x4 acc[4][4];
#pragma unroll
    for (int i = 0; i < 4; ++i)
#pragma unroll
        for (int j = 0; j < 4; ++j) acc[i][j] = (f32x4){0.f, 0.f, 0.f, 0.f};

    const int fr = lane & 15, kg = (lane >> 4) * 8;

    for (int ks = 0; ks < K; ks += 32) {
        float4 a0 = make_float4(0.f, 0.f, 0.f, 0.f), a1 = a0;
        if (aval) {
            a0 = *(const float4*)&Arow[ks + sak];
            a1 = *(const float4*)&Arow[ks + sak + 4];
        }
        uint4 wh0 = *(const uint4*)&Wrh[ks];
        uint4 wh1 = *(const uint4*)&Wrh[ks + 8];
        uint4 wh2 = *(const uint4*)&Wrh[ks + 16];
        uint4 wh3 = *(const uint4*)&Wrh[ks + 24];
        uint4 wl0 = *(const uint4*)&Wrl[ks];
        uint4 wl1 = *(const uint4*)&Wrl[ks + 8];
        uint4 wl2 = *(const uint4*)&Wrl[ks + 16];
        uint4 wl3 = *(const uint4*)&Wrl[ks + 24];

        __syncthreads();   // previous iteration's frag reads complete

        // A: convert fp32 -> hi/lo and store
        {
            float va[8] = {a0.x, a0.y, a0.z, a0.w, a1.x, a1.y, a1.z, a1.w};
            bf16x8 hv, lv;
#pragma unroll
            for (int e = 0; e < 8; ++e) {
                float v = va[e];
                __bf16 h = (__bf16)v;
                hv[e] = h;
                lv[e] = (__bf16)(v - (float)h);
            }
            *(bf16x8*)&Ah[sar][sak] = hv;
            *(bf16x8*)&Al[sar][sak] = lv;
        }
        // B: straight copy of pre-split weights
        *(uint4*)&Bh[tid][0]  = wh0;
        *(uint4*)&Bh[tid][8]  = wh1;
        *(uint4*)&Bh[tid][16] = wh2;
        *(uint4*)&Bh[tid][24] = wh3;
        *(uint4*)&Bl[tid][0]  = wl0;
        *(uint4*)&Bl[tid][8]  = wl1;
        *(uint4*)&Bl[tid][16] = wl2;
        *(uint4*)&Bl[tid][24] = wl3;

        __syncthreads();

        bf16x8 ah[4], al[4], bh[4], bl[4];
#pragma unroll
        for (int mt = 0; mt < 4; ++mt) {
            ah[mt] = *(const bf16x8*)&Ah[mt * 16 + fr][kg];
            al[mt] = *(const bf16x8*)&Al[mt * 16 + fr][kg];
        }
#pragma unroll
        for (int nt = 0; nt < 4; ++nt) {
            bh[nt] = *(const bf16x8*)&Bh[wv * 64 + nt * 16 + fr][kg];
            bl[nt] = *(const bf16x8*)&Bl[wv * 64 + nt * 16 + fr][kg];
        }
#pragma unroll
        for (int mt = 0; mt < 4; ++mt)
#pragma unroll
            for (int nt = 0; nt < 4; ++nt) {
                acc[mt][nt] = __builtin_amdgcn_mfma_f32_16x16x32_bf16(ah[mt], bh[nt], acc[mt][nt], 0, 0, 0);
                acc[mt][nt] = __builtin_amdgcn_mfma_f32_16x16x32_bf16(ah[mt], bl[nt], acc[mt][nt], 0, 0, 0);
                acc[mt][nt] = __builtin_amdgcn_mfma_f32_16x16x32_bf16(al[mt], bh[nt], acc[mt][nt], 0, 0, 0);
            }
    }

    // ---------------- epilogue ----------------
    const int q4 = (lane >> 4) * 4;
    const int cb = bn + wv * 64;    // wave's global col base

    if (MODE == 1) {
        float s0 = 0.f, s1 = 0.f, s2 = 0.f, s3 = 0.f;
        int cur = -1;
        float bi0 = bias[cb + 0 * 16 + fr], bi1 = bias[cb + 1 * 16 + fr];
        float bi2 = bias[cb + 2 * 16 + fr], bi3 = bias[cb + 3 * 16 + fr];
#pragma unroll
        for (int mt = 0; mt < 4; ++mt) {
#pragma unroll
            for (int j = 0; j < 4; ++j) {
                int m = bm + mt * 16 + q4 + j;
                if (m < M) {
                    float v0 = acc[mt][0][j] + bi0;
                    float v1 = acc[mt][1][j] + bi1;
                    float v2 = acc[mt][2][j] + bi2;
                    float v3 = acc[mt][3][j] + bi3;
                    if (ACT == 1) {
                        v0 = v0 >= 0.f ? v0 : 0.01f * v0;
                        v1 = v1 >= 0.f ? v1 : 0.01f * v1;
                        v2 = v2 >= 0.f ? v2 : 0.01f * v2;
                        v3 = v3 >= 0.f ? v3 : 0.01f * v3;
                    }
                    int b = aux[m];
                    if (b != cur) {
                        if (cur >= 0) {
                            atomicAdd(&out[(size_t)cur * ldo + cb + 0 * 16 + fr], s0);
                            atomicAdd(&out[(size_t)cur * ldo + cb + 1 * 16 + fr], s1);
                            atomicAdd(&out[(size_t)cur * ldo + cb + 2 * 16 + fr], s2);
                            atomicAdd(&out[(size_t)cur * ldo + cb + 3 * 16 + fr], s3);
                        }
                        cur = b; s0 = v0; s1 = v1; s2 = v2; s3 = v3;
                    } else {
                        s0 += v0; s1 += v1; s2 += v2; s3 += v3;
                    }
                }
            }
        }
        if (cur >= 0) {
            atomicAdd(&out[(size_t)cur * ldo + cb + 0 * 16 + fr], s0);
            atomicAdd(&out[(size_t)cur * ldo + cb + 1 * 16 + fr], s1);
            atomicAdd(&out[(size_t)cur * ldo + cb + 2 * 16 + fr], s2);
            atomicAdd(&out[(size_t)cur * ldo + cb + 3 * 16 + fr], s3);
        }
    } else {
#pragma unroll
        for (int mt = 0; mt < 4; ++mt) {
#pragma unroll
            for (int j = 0; j < 4; ++j) {
                int m = bm + mt * 16 + q4 + j;
                if (m >= M) continue;
                size_t obase;
                if (MODE == 2) {
                    int orow = (m < GB) ? m : m - GB;
                    int ocol = (m < GB) ? 256 : 512;
                    obase = (size_t)orow * ldo + ocol;
                } else {
                    obase = (size_t)m * ldo;
                }
#pragma unroll
                for (int nt = 0; nt < 4; ++nt) {
                    int cc = cb + nt * 16 + fr;
                    float v = acc[mt][nt][j] + bias[cc];
                    if (ACT == 1) v = v >= 0.f ? v : 0.01f * v;
                    if (ACT == 2) v = tanhf(v);
                    out[obase + cc] = v;
                }
            }
        }
    }
}

// ---------------- output head (fp32, tiny) ----------------
__global__ void outhead_kernel(const float* __restrict__ h, const float* __restrict__ W,
                               const float* __restrict__ bias, float* __restrict__ yp, int nout) {
    int idx = blockIdx.x * 256 + threadIdx.x;
    if (idx >= GB * nout) return;
    int b = idx / nout, o = idx - b * nout;
    const float4* hr = (const float4*)(h + (size_t)b * 512);
    const float4* wr = (const float4*)(W + (size_t)o * 512);
    float s = 0.f;
#pragma unroll 4
    for (int k = 0; k < 128; ++k) {
        float4 hv = hr[k], wv = wr[k];
        s = fmaf(hv.x, wv.x, s);
        s = fmaf(hv.y, wv.y, s);
        s = fmaf(hv.z, wv.z, s);
        s = fmaf(hv.w, wv.w, s);
    }
    yp[b * nout + o] = s + bias[o];
}

// ---------------- losses ----------------
__global__ void loss_kernel(const float* __restrict__ ypx, const float* __restrict__ ypA,
                            const float* __restrict__ y_x, const float* __restrict__ y_A,
                            float* __restrict__ out) {
    int b = blockIdx.x * 256 + threadIdx.x;
    if (b >= GB) return;
#pragma unroll
    for (int j = 0; j < 2; ++j) {
        float p  = ypx[b * 4 + j];
        float a  = p * p + 1e-7f;
        float mu = ypx[b * 4 + 2 + j];
        float e  = (y_x[b * 2 + j] - mu) / a;
        out[b * 2 + j] = e * e + logf(a);
    }
    float p  = ypA[b * 2 + 0];
    float a  = p * p + 1e-7f;
    float mu = ypA[b * 2 + 1];
    float e  = (y_A[b] - mu) / a;
    out[2 * GB + b] = e * e + logf(a);
}

extern "C" void kernel_launch(void* const* d_in, const int* in_sizes, int n_in,
                              void* d_out, int out_size, void* d_ws, size_t ws_size,
                              hipStream_t stream) {
    const float* x_x     = (const float*)d_in[0];
    const float* y_x     = (const float*)d_in[1];
    const int*   ei_x    = (const int*)d_in[2];
    const int*   batch_x = (const int*)d_in[3];
    const float* x_A     = (const float*)d_in[4];
    const float* y_A     = (const float*)d_in[5];
    const int*   ei_A    = (const int*)d_in[6];
    const int*   batch_A = (const int*)d_in[7];
    const int*   idi_A   = (const int*)d_in[8];
    const int*   idj_A   = (const int*)d_in[9];
    const float* W1r = (const float*)d_in[10];
    const float* W1n = (const float*)d_in[11];
    const float* b1  = (const float*)d_in[12];
    const float* W2r = (const float*)d_in[13];
    const float* W2n = (const float*)d_in[14];
    const float* b2  = (const float*)d_in[15];
    const float* nW1 = (const float*)d_in[16];
    const float* nb1 = (const float*)d_in[17];
    const float* nW2 = (const float*)d_in[18];
    const float* nb2 = (const float*)d_in[19];
    const float* nW3 = (const float*)d_in[20];
    const float* nb3 = (const float*)d_in[21];
    const float* eW1 = (const float*)d_in[22];
    const float* eb1 = (const float*)d_in[23];
    const float* eW2 = (const float*)d_in[24];
    const float* eb2 = (const float*)d_in[25];
    const float* eW3 = (const float*)d_in[26];
    const float* eb3 = (const float*)d_in[27];

    // ---- workspace layout ----
    float* ws = (float*)d_ws;
    float* gm   = ws;                       // 51,200,000 f
    float* msg1 = gm   + (size_t)GN * 256;  //    400,000 f
    float* rgx  = msg1 + (size_t)GN * 2;    //  2,560,000 f
    float* use  = rgx  + (size_t)GB * 256;  //  7,680,000 f
    __bf16* wpool = (__bf16*)(use + (size_t)GB * 768);
    __bf16* wcat_hi = wpool;                // 65536
    __bf16* wcat_lo = wcat_hi + 65536;
    __bf16* nW1hi = wcat_lo + 65536;        // 65536
    __bf16* nW1lo = nW1hi + 65536;
    __bf16* nW2hi = nW1lo + 65536;          // 131072
    __bf16* nW2lo = nW2hi + 131072;
    __bf16* eW1hi = nW2lo + 131072;         // 196608
    __bf16* eW1lo = eW1hi + 196608;
    __bf16* eW2hi = eW1lo + 196608;         // 131072
    __bf16* eW2lo = eW2hi + 131072;
    char*   wend  = (char*)(eW2lo + 131072);
    // aliases into gm (dead after sel-GEMM):
    float* h1  = gm;
    float* h2  = h1 + (size_t)GB * 256;
    float* ypx = h2 + (size_t)GB * 512;
    float* ypA = ypx + (size_t)GB * 4;

    size_t need = (size_t)(wend - (char*)d_ws);
    if (ws_size < need) return;

    float* out = (float*)d_out;

    // weight prep (bf16 hi/lo split)
    prep_wcat_split<<<256, 256, 0, stream>>>(W2r, W2n, wcat_hi, wcat_lo);
    prep_split<<<256, 256, 0, stream>>>(nW1, nW1hi, nW1lo, 65536);
    prep_split<<<512, 256, 0, stream>>>(nW2, nW2hi, nW2lo, 131072);
    prep_split<<<768, 256, 0, stream>>>(eW1, eW1hi, eW1lo, 196608);
    prep_split<<<512, 256, 0, stream>>>(eW2, eW2hi, eW2lo, 131072);

    const int conv2_grid = GN / 64;                 // 3125
    const int sel_grid   = (2 * GB + 63) / 64;      // 313
    const int mlp_mt     = (GB + 63) / 64;          // 157

    for (int g = 0; g < 2; ++g) {
        const float* x   = g == 0 ? x_x : x_A;
        const int*   src = (g == 0 ? ei_x : ei_A);
        const int*   dst = src + GE;
        const int*   bat = g == 0 ? batch_x : batch_A;

        hipMemsetAsync(msg1, 0, (size_t)GN * 2 * sizeof(float), stream);
        scatter1_kernel<<<(GE + 255) / 256, 256, 0, stream>>>(x, src, dst, msg1);
        conv1_kernel<<<GN * 128 / 256, 256, 0, stream>>>(x, msg1, W1r, W1n, b1, gm);
        scatter2_kernel<<<GE * 128 / 256, 256, 0, stream>>>(gm, src, dst, gm);

        if (g == 0) {
            hipMemsetAsync(rgx, 0, (size_t)GB * 256 * sizeof(float), stream);
            mfma_gemm_kernel<1, 1><<<conv2_grid, 256, 0, stream>>>(
                gm, 256, wcat_hi, wcat_lo, b2, rgx, 256, GN, 256, 1, bat, nullptr);
        } else {
            hipMemsetAsync(use, 0, (size_t)GB * 768 * sizeof(float), stream);
            mfma_gemm_kernel<1, 1><<<conv2_grid, 256, 0, stream>>>(
                gm, 256, wcat_hi, wcat_lo, b2, use, 768, GN, 256, 1, bat, nullptr);
            mfma_gemm_kernel<1, 2><<<sel_grid, 256, 0, stream>>>(
                gm, 256, wcat_hi, wcat_lo, b2, use, 768, 2 * GB, 256, 1, idi_A, idj_A);
        }
    }

    // node MLP (h1/h2 alias gm; gm dead now)
    mfma_gemm_kernel<2, 0><<<mlp_mt, 256, 0, stream>>>(
        rgx, 256, nW1hi, nW1lo, nb1, h1, 256, GB, 256, 1, nullptr, nullptr);
    mfma_gemm_kernel<2, 0><<<mlp_mt * 2, 256, 0, stream>>>(
        h1, 256, nW2hi, nW2lo, nb2, h2, 512, GB, 256, 2, nullptr, nullptr);
    outhead_kernel<<<(GB * 4 + 255) / 256, 256, 0, stream>>>(h2, nW3, nb3, ypx, 4);

    // edge MLP
    mfma_gemm_kernel<2, 0><<<mlp_mt, 256, 0, stream>>>(
        use, 768, eW1hi, eW1lo, eb1, h1, 256, GB, 768, 1, nullptr, nullptr);
    mfma_gemm_kernel<2, 0><<<mlp_mt * 2, 256, 0, stream>>>(
        h1, 256, eW2hi, eW2lo, eb2, h2, 512, GB, 256, 2, nullptr, nullptr);
    outhead_kernel<<<(GB * 2 + 255) / 256, 256, 0, stream>>>(h2, eW3, eb3, ypA, 2);

    loss_kernel<<<(GB + 255) / 256, 256, 0, stream>>>(ypx, ypA, y_x, y_A, out);
}

// Round 4
// 978.504 us; speedup vs baseline: 2.5754x; 1.3802x over previous
//
#include <hip/hip_runtime.h>
#include <hip/hip_bf16.h>

#define GN 200000
#define GB 10000
#define GE 600000
#define NCHUNK 98   // ceil(GN/2048)

typedef __bf16 bf16x8 __attribute__((ext_vector_type(8)));
typedef float  f32x4  __attribute__((ext_vector_type(4)));

// ---------------- CSR construction ----------------
__global__ void deg_kernel(const int* __restrict__ dst, int* __restrict__ deg) {
    int e = blockIdx.x * 256 + threadIdx.x;
    if (e >= GE) return;
    atomicAdd(&deg[dst[e]], 1);
}

// in-place exclusive scan, chunk = 2048 (512 thr x 4)
__global__ void scan1_kernel(int* __restrict__ data, int* __restrict__ csum, int n) {
    __shared__ int ls[512];
    int b = blockIdx.x, t = threadIdx.x;
    int base = b * 2048 + t * 4;
    int v0 = base + 0 < n ? data[base + 0] : 0;
    int v1 = base + 1 < n ? data[base + 1] : 0;
    int v2 = base + 2 < n ? data[base + 2] : 0;
    int v3 = base + 3 < n ? data[base + 3] : 0;
    int s = v0 + v1 + v2 + v3;
    ls[t] = s;
    __syncthreads();
    for (int off = 1; off < 512; off <<= 1) {
        int x = (t >= off) ? ls[t - off] : 0;
        __syncthreads();
        ls[t] += x;
        __syncthreads();
    }
    int excl = ls[t] - s;
    if (t == 511) csum[b] = ls[511];
    if (base + 0 < n) data[base + 0] = excl;
    if (base + 1 < n) data[base + 1] = excl + v0;
    if (base + 2 < n) data[base + 2] = excl + v0 + v1;
    if (base + 3 < n) data[base + 3] = excl + v0 + v1 + v2;
}

__global__ void scan2_kernel(int* __restrict__ csum, int nchunks) {
    __shared__ int ls[128];
    int t = threadIdx.x;
    int v = (t < nchunks) ? csum[t] : 0;
    ls[t] = v;
    __syncthreads();
    for (int off = 1; off < 128; off <<= 1) {
        int x = (t >= off) ? ls[t - off] : 0;
        __syncthreads();
        ls[t] += x;
        __syncthreads();
    }
    if (t < nchunks) csum[t] = ls[t] - v;   // exclusive
}

__global__ void scan3_kernel(int* __restrict__ rowptr, int* __restrict__ cursor,
                             const int* __restrict__ csum, int n) {
    int i = blockIdx.x * 256 + threadIdx.x;
    if (i >= n) return;
    int v = rowptr[i] + csum[i >> 11];
    rowptr[i] = v;
    cursor[i] = v;
}

__global__ void fill_csr_kernel(const int* __restrict__ src, const int* __restrict__ dst,
                                int* __restrict__ cursor, int* __restrict__ eidx) {
    int e = blockIdx.x * 256 + threadIdx.x;
    if (e >= GE) return;
    int p = atomicAdd(&cursor[dst[e]], 1);
    eidx[p] = src[e];
}
// after fill: rowptr[n] = start, cursor[n] = end

// ---------------- message passing via CSR (gather, no atomics) ----------------
__global__ void msg1_csr_kernel(const float* __restrict__ x, const int* __restrict__ rowptr,
                                const int* __restrict__ cursor, const int* __restrict__ eidx,
                                float* __restrict__ msg1) {
    int n = blockIdx.x * 256 + threadIdx.x;
    if (n >= GN) return;
    int k = rowptr[n], k1 = cursor[n];
    float a0 = 0.f, a1 = 0.f;
    for (; k + 1 < k1; k += 2) {
        int sa = eidx[k], sb = eidx[k + 1];
        float2 va = *(const float2*)&x[sa * 2];
        float2 vb = *(const float2*)&x[sb * 2];
        a0 += va.x + vb.x;
        a1 += va.y + vb.y;
    }
    if (k < k1) {
        int sa = eidx[k];
        float2 va = *(const float2*)&x[sa * 2];
        a0 += va.x;
        a1 += va.y;
    }
    msg1[n * 2] = a0;
    msg1[n * 2 + 1] = a1;
}

// wave per node: 64 lanes x float2 = 128 channels
__global__ void msg2_csr_kernel(const float* __restrict__ gm, const int* __restrict__ rowptr,
                                const int* __restrict__ cursor, const int* __restrict__ eidx,
                                float* __restrict__ gmw) {
    int wid = (blockIdx.x * 256 + threadIdx.x) >> 6;
    int lane = threadIdx.x & 63;
    if (wid >= GN) return;
    int k = rowptr[wid], k1 = cursor[wid];
    float a0 = 0.f, a1 = 0.f;
    for (; k + 1 < k1; k += 2) {
        int sa = eidx[k], sb = eidx[k + 1];
        float2 va = *(const float2*)&gm[(size_t)sa * 256 + lane * 2];
        float2 vb = *(const float2*)&gm[(size_t)sb * 256 + lane * 2];
        a0 += va.x + vb.x;
        a1 += va.y + vb.y;
    }
    if (k < k1) {
        int sa = eidx[k];
        float2 va = *(const float2*)&gm[(size_t)sa * 256 + lane * 2];
        a0 += va.x;
        a1 += va.y;
    }
    *(float2*)&gmw[(size_t)wid * 256 + 128 + lane * 2] = make_float2(a0, a1);
}

// ---------------- conv layer 1 (g1 half only; msg2 half written by msg2_csr) ----------------
__global__ void conv1_kernel(const float* __restrict__ x, const float* __restrict__ msg1,
                             const float* __restrict__ W1r, const float* __restrict__ W1n,
                             const float* __restrict__ b1, float* __restrict__ gm) {
    int idx = blockIdx.x * 256 + threadIdx.x;   // n*128 + c
    int n = idx >> 7, c = idx & 127;
    float x0 = x[n * 2], x1 = x[n * 2 + 1];
    float m0 = msg1[n * 2], m1 = msg1[n * 2 + 1];
    float v = b1[c];
    v = fmaf(x0, W1r[c * 2], v);
    v = fmaf(x1, W1r[c * 2 + 1], v);
    v = fmaf(m0, W1n[c * 2], v);
    v = fmaf(m1, W1n[c * 2 + 1], v);
    v = v >= 0.f ? v : 0.01f * v;
    gm[(size_t)n * 256 + c] = v;
}

// ---------------- weight prep: fp32 -> bf16 hi/lo ----------------
__global__ void prep_wcat_split(const float* __restrict__ W2r, const float* __restrict__ W2n,
                                __bf16* __restrict__ hi, __bf16* __restrict__ lo) {
    int idx = blockIdx.x * 256 + threadIdx.x;   // c*256 + k
    int c = idx >> 8, k = idx & 255;
    float v = (k < 128) ? W2r[c * 128 + k] : W2n[c * 128 + (k - 128)];
    __bf16 h = (__bf16)v;
    hi[idx] = h;
    lo[idx] = (__bf16)(v - (float)h);
}

__global__ void prep_split(const float* __restrict__ W, __bf16* __restrict__ hi,
                           __bf16* __restrict__ lo, int n) {
    int i = blockIdx.x * 256 + threadIdx.x;
    if (i >= n) return;
    float v = W[i];
    __bf16 h = (__bf16)v;
    hi[i] = h;
    lo[i] = (__bf16)(v - (float)h);
}

// ---------------- MFMA split-bf16 GEMM (unchanged from round 3) ----------------
template <int ACT, int MODE>
__global__ __launch_bounds__(256, 2)
void mfma_gemm_kernel(const float* __restrict__ A, int lda,
                      const __bf16* __restrict__ whi, const __bf16* __restrict__ wlo,
                      const float* __restrict__ bias,
                      float* __restrict__ out, int ldo,
                      int M, int K, int ctiles,
                      const int* __restrict__ aux, const int* __restrict__ aux2) {
    __shared__ __bf16 Ah[64][40], Al[64][40], Bh[256][40], Bl[256][40];
    const int bm = (blockIdx.x / ctiles) * 64;
    const int bn = (blockIdx.x % ctiles) * 256;
    const int tid = threadIdx.x, lane = tid & 63, wv = tid >> 6;

    const int sar = tid >> 2;
    const int sak = (tid & 3) * 8;
    const int arow = bm + sar;
    long asrc = arow;
    if (MODE == 2) asrc = (arow < M) ? (arow < GB ? aux[arow] : aux2[arow - GB]) : 0;
    const bool aval = (arow < M);
    const float* Arow = A + (size_t)asrc * lda;
    const __bf16* Wrh = whi + (size_t)(bn + tid) * K;
    const __bf16* Wrl = wlo + (size_t)(bn + tid) * K;

    f32x4 acc[4][4];
#pragma unroll
    for (int i = 0; i < 4; ++i)
#pragma unroll
        for (int j = 0; j < 4; ++j) acc[i][j] = (f32x4){0.f, 0.f, 0.f, 0.f};

    const int fr = lane & 15, kg = (lane >> 4) * 8;

    for (int ks = 0; ks < K; ks += 32) {
        float4 a0 = make_float4(0.f, 0.f, 0.f, 0.f), a1 = a0;
        if (aval) {
            a0 = *(const float4*)&Arow[ks + sak];
            a1 = *(const float4*)&Arow[ks + sak + 4];
        }
        uint4 wh0 = *(const uint4*)&Wrh[ks];
        uint4 wh1 = *(const uint4*)&Wrh[ks + 8];
        uint4 wh2 = *(const uint4*)&Wrh[ks + 16];
        uint4 wh3 = *(const uint4*)&Wrh[ks + 24];
        uint4 wl0 = *(const uint4*)&Wrl[ks];
        uint4 wl1 = *(const uint4*)&Wrl[ks + 8];
        uint4 wl2 = *(const uint4*)&Wrl[ks + 16];
        uint4 wl3 = *(const uint4*)&Wrl[ks + 24];

        __syncthreads();

        {
            float va[8] = {a0.x, a0.y, a0.z, a0.w, a1.x, a1.y, a1.z, a1.w};
            bf16x8 hv, lv;
#pragma unroll
            for (int e = 0; e < 8; ++e) {
                float v = va[e];
                __bf16 h = (__bf16)v;
                hv[e] = h;
                lv[e] = (__bf16)(v - (float)h);
            }
            *(bf16x8*)&Ah[sar][sak] = hv;
            *(bf16x8*)&Al[sar][sak] = lv;
        }
        *(uint4*)&Bh[tid][0]  = wh0;
        *(uint4*)&Bh[tid][8]  = wh1;
        *(uint4*)&Bh[tid][16] = wh2;
        *(uint4*)&Bh[tid][24] = wh3;
        *(uint4*)&Bl[tid][0]  = wl0;
        *(uint4*)&Bl[tid][8]  = wl1;
        *(uint4*)&Bl[tid][16] = wl2;
        *(uint4*)&Bl[tid][24] = wl3;

        __syncthreads();

        bf16x8 ah[4], al[4], bh[4], bl[4];
#pragma unroll
        for (int mt = 0; mt < 4; ++mt) {
            ah[mt] = *(const bf16x8*)&Ah[mt * 16 + fr][kg];
            al[mt] = *(const bf16x8*)&Al[mt * 16 + fr][kg];
        }
#pragma unroll
        for (int nt = 0; nt < 4; ++nt) {
            bh[nt] = *(const bf16x8*)&Bh[wv * 64 + nt * 16 + fr][kg];
            bl[nt] = *(const bf16x8*)&Bl[wv * 64 + nt * 16 + fr][kg];
        }
#pragma unroll
        for (int mt = 0; mt < 4; ++mt)
#pragma unroll
            for (int nt = 0; nt < 4; ++nt) {
                acc[mt][nt] = __builtin_amdgcn_mfma_f32_16x16x32_bf16(ah[mt], bh[nt], acc[mt][nt], 0, 0, 0);
                acc[mt][nt] = __builtin_amdgcn_mfma_f32_16x16x32_bf16(ah[mt], bl[nt], acc[mt][nt], 0, 0, 0);
                acc[mt][nt] = __builtin_amdgcn_mfma_f32_16x16x32_bf16(al[mt], bh[nt], acc[mt][nt], 0, 0, 0);
            }
    }

    const int q4 = (lane >> 4) * 4;
    const int cb = bn + wv * 64;

    if (MODE == 1) {
        float s0 = 0.f, s1 = 0.f, s2 = 0.f, s3 = 0.f;
        int cur = -1;
        float bi0 = bias[cb + 0 * 16 + fr], bi1 = bias[cb + 1 * 16 + fr];
        float bi2 = bias[cb + 2 * 16 + fr], bi3 = bias[cb + 3 * 16 + fr];
#pragma unroll
        for (int mt = 0; mt < 4; ++mt) {
#pragma unroll
            for (int j = 0; j < 4; ++j) {
                int m = bm + mt * 16 + q4 + j;
                if (m < M) {
                    float v0 = acc[mt][0][j] + bi0;
                    float v1 = acc[mt][1][j] + bi1;
                    float v2 = acc[mt][2][j] + bi2;
                    float v3 = acc[mt][3][j] + bi3;
                    if (ACT == 1) {
                        v0 = v0 >= 0.f ? v0 : 0.01f * v0;
                        v1 = v1 >= 0.f ? v1 : 0.01f * v1;
                        v2 = v2 >= 0.f ? v2 : 0.01f * v2;
                        v3 = v3 >= 0.f ? v3 : 0.01f * v3;
                    }
                    int b = aux[m];
                    if (b != cur) {
                        if (cur >= 0) {
                            atomicAdd(&out[(size_t)cur * ldo + cb + 0 * 16 + fr], s0);
                            atomicAdd(&out[(size_t)cur * ldo + cb + 1 * 16 + fr], s1);
                            atomicAdd(&out[(size_t)cur * ldo + cb + 2 * 16 + fr], s2);
                            atomicAdd(&out[(size_t)cur * ldo + cb + 3 * 16 + fr], s3);
                        }
                        cur = b; s0 = v0; s1 = v1; s2 = v2; s3 = v3;
                    } else {
                        s0 += v0; s1 += v1; s2 += v2; s3 += v3;
                    }
                }
            }
        }
        if (cur >= 0) {
            atomicAdd(&out[(size_t)cur * ldo + cb + 0 * 16 + fr], s0);
            atomicAdd(&out[(size_t)cur * ldo + cb + 1 * 16 + fr], s1);
            atomicAdd(&out[(size_t)cur * ldo + cb + 2 * 16 + fr], s2);
            atomicAdd(&out[(size_t)cur * ldo + cb + 3 * 16 + fr], s3);
        }
    } else {
#pragma unroll
        for (int mt = 0; mt < 4; ++mt) {
#pragma unroll
            for (int j = 0; j < 4; ++j) {
                int m = bm + mt * 16 + q4 + j;
                if (m >= M) continue;
                size_t obase;
                if (MODE == 2) {
                    int orow = (m < GB) ? m : m - GB;
                    int ocol = (m < GB) ? 256 : 512;
                    obase = (size_t)orow * ldo + ocol;
                } else {
                    obase = (size_t)m * ldo;
                }
#pragma unroll
                for (int nt = 0; nt < 4; ++nt) {
                    int cc = cb + nt * 16 + fr;
                    float v = acc[mt][nt][j] + bias[cc];
                    if (ACT == 1) v = v >= 0.f ? v : 0.01f * v;
                    if (ACT == 2) v = tanhf(v);
                    out[obase + cc] = v;
                }
            }
        }
    }
}

// ---------------- output head ----------------
__global__ void outhead_kernel(const float* __restrict__ h, const float* __restrict__ W,
                               const float* __restrict__ bias, float* __restrict__ yp, int nout) {
    int idx = blockIdx.x * 256 + threadIdx.x;
    if (idx >= GB * nout) return;
    int b = idx / nout, o = idx - b * nout;
    const float4* hr = (const float4*)(h + (size_t)b * 512);
    const float4* wr = (const float4*)(W + (size_t)o * 512);
    float s = 0.f;
#pragma unroll 4
    for (int k = 0; k < 128; ++k) {
        float4 hv = hr[k], wv = wr[k];
        s = fmaf(hv.x, wv.x, s);
        s = fmaf(hv.y, wv.y, s);
        s = fmaf(hv.z, wv.z, s);
        s = fmaf(hv.w, wv.w, s);
    }
    yp[b * nout + o] = s + bias[o];
}

// ---------------- losses ----------------
__global__ void loss_kernel(const float* __restrict__ ypx, const float* __restrict__ ypA,
                            const float* __restrict__ y_x, const float* __restrict__ y_A,
                            float* __restrict__ out) {
    int b = blockIdx.x * 256 + threadIdx.x;
    if (b >= GB) return;
#pragma unroll
    for (int j = 0; j < 2; ++j) {
        float p  = ypx[b * 4 + j];
        float a  = p * p + 1e-7f;
        float mu = ypx[b * 4 + 2 + j];
        float e  = (y_x[b * 2 + j] - mu) / a;
        out[b * 2 + j] = e * e + logf(a);
    }
    float p  = ypA[b * 2 + 0];
    float a  = p * p + 1e-7f;
    float mu = ypA[b * 2 + 1];
    float e  = (y_A[b] - mu) / a;
    out[2 * GB + b] = e * e + logf(a);
}

extern "C" void kernel_launch(void* const* d_in, const int* in_sizes, int n_in,
                              void* d_out, int out_size, void* d_ws, size_t ws_size,
                              hipStream_t stream) {
    const float* x_x     = (const float*)d_in[0];
    const float* y_x     = (const float*)d_in[1];
    const int*   ei_x    = (const int*)d_in[2];
    const int*   batch_x = (const int*)d_in[3];
    const float* x_A     = (const float*)d_in[4];
    const float* y_A     = (const float*)d_in[5];
    const int*   ei_A    = (const int*)d_in[6];
    const int*   batch_A = (const int*)d_in[7];
    const int*   idi_A   = (const int*)d_in[8];
    const int*   idj_A   = (const int*)d_in[9];
    const float* W1r = (const float*)d_in[10];
    const float* W1n = (const float*)d_in[11];
    const float* b1  = (const float*)d_in[12];
    const float* W2r = (const float*)d_in[13];
    const float* W2n = (const float*)d_in[14];
    const float* b2  = (const float*)d_in[15];
    const float* nW1 = (const float*)d_in[16];
    const float* nb1 = (const float*)d_in[17];
    const float* nW2 = (const float*)d_in[18];
    const float* nb2 = (const float*)d_in[19];
    const float* nW3 = (const float*)d_in[20];
    const float* nb3 = (const float*)d_in[21];
    const float* eW1 = (const float*)d_in[22];
    const float* eb1 = (const float*)d_in[23];
    const float* eW2 = (const float*)d_in[24];
    const float* eb2 = (const float*)d_in[25];
    const float* eW3 = (const float*)d_in[26];
    const float* eb3 = (const float*)d_in[27];

    // ---- workspace layout ----
    float* ws = (float*)d_ws;
    float* gm   = ws;                       // 51,200,000 f
    float* msg1 = gm   + (size_t)GN * 256;  //    400,000 f
    float* rgx  = msg1 + (size_t)GN * 2;    //  2,560,000 f
    float* use  = rgx  + (size_t)GB * 256;  //  7,680,000 f
    __bf16* wpool = (__bf16*)(use + (size_t)GB * 768);
    __bf16* wcat_hi = wpool;
    __bf16* wcat_lo = wcat_hi + 65536;
    __bf16* nW1hi = wcat_lo + 65536;
    __bf16* nW1lo = nW1hi + 65536;
    __bf16* nW2hi = nW1lo + 65536;
    __bf16* nW2lo = nW2hi + 131072;
    __bf16* eW1hi = nW2lo + 131072;
    __bf16* eW1lo = eW1hi + 196608;
    __bf16* eW2hi = eW1lo + 196608;
    __bf16* eW2lo = eW2hi + 131072;
    // CSR arrays
    int* rowptr = (int*)(eW2lo + 131072);   // GN
    int* cursor = rowptr + GN;              // GN
    int* eidx   = cursor + GN;              // GE
    int* csum   = eidx + GE;                // 256
    char* wend  = (char*)(csum + 256);
    // aliases into gm (dead after sel-GEMM):
    float* h1  = gm;
    float* h2  = h1 + (size_t)GB * 256;
    float* ypx = h2 + (size_t)GB * 512;
    float* ypA = ypx + (size_t)GB * 4;

    size_t need = (size_t)(wend - (char*)d_ws);
    if (ws_size < need) return;

    float* out = (float*)d_out;

    // weight prep (bf16 hi/lo split)
    prep_wcat_split<<<256, 256, 0, stream>>>(W2r, W2n, wcat_hi, wcat_lo);
    prep_split<<<256, 256, 0, stream>>>(nW1, nW1hi, nW1lo, 65536);
    prep_split<<<512, 256, 0, stream>>>(nW2, nW2hi, nW2lo, 131072);
    prep_split<<<768, 256, 0, stream>>>(eW1, eW1hi, eW1lo, 196608);
    prep_split<<<512, 256, 0, stream>>>(eW2, eW2hi, eW2lo, 131072);

    const int conv2_grid = GN / 64;                 // 3125
    const int sel_grid   = (2 * GB + 63) / 64;      // 313
    const int mlp_mt     = (GB + 63) / 64;          // 157
    const int eg         = (GE + 255) / 256;

    for (int g = 0; g < 2; ++g) {
        const float* x   = g == 0 ? x_x : x_A;
        const int*   src = (g == 0 ? ei_x : ei_A);
        const int*   dst = src + GE;
        const int*   bat = g == 0 ? batch_x : batch_A;

        // build CSR (by destination)
        hipMemsetAsync(rowptr, 0, (size_t)GN * sizeof(int), stream);
        deg_kernel<<<eg, 256, 0, stream>>>(dst, rowptr);
        scan1_kernel<<<NCHUNK, 512, 0, stream>>>(rowptr, csum, GN);
        scan2_kernel<<<1, 128, 0, stream>>>(csum, NCHUNK);
        scan3_kernel<<<(GN + 255) / 256, 256, 0, stream>>>(rowptr, cursor, csum, GN);
        fill_csr_kernel<<<eg, 256, 0, stream>>>(src, dst, cursor, eidx);

        // message passing + conv1
        msg1_csr_kernel<<<(GN + 255) / 256, 256, 0, stream>>>(x, rowptr, cursor, eidx, msg1);
        conv1_kernel<<<GN * 128 / 256, 256, 0, stream>>>(x, msg1, W1r, W1n, b1, gm);
        msg2_csr_kernel<<<GN / 4, 256, 0, stream>>>(gm, rowptr, cursor, eidx, gm);

        if (g == 0) {
            hipMemsetAsync(rgx, 0, (size_t)GB * 256 * sizeof(float), stream);
            mfma_gemm_kernel<1, 1><<<conv2_grid, 256, 0, stream>>>(
                gm, 256, wcat_hi, wcat_lo, b2, rgx, 256, GN, 256, 1, bat, nullptr);
        } else {
            hipMemsetAsync(use, 0, (size_t)GB * 768 * sizeof(float), stream);
            mfma_gemm_kernel<1, 1><<<conv2_grid, 256, 0, stream>>>(
                gm, 256, wcat_hi, wcat_lo, b2, use, 768, GN, 256, 1, bat, nullptr);
            mfma_gemm_kernel<1, 2><<<sel_grid, 256, 0, stream>>>(
                gm, 256, wcat_hi, wcat_lo, b2, use, 768, 2 * GB, 256, 1, idi_A, idj_A);
        }
    }

    // node MLP (h1/h2 alias gm; gm dead now)
    mfma_gemm_kernel<2, 0><<<mlp_mt, 256, 0, stream>>>(
        rgx, 256, nW1hi, nW1lo, nb1, h1, 256, GB, 256, 1, nullptr, nullptr);
    mfma_gemm_kernel<2, 0><<<mlp_mt * 2, 256, 0, stream>>>(
        h1, 256, nW2hi, nW2lo, nb2, h2, 512, GB, 256, 2, nullptr, nullptr);
    outhead_kernel<<<(GB * 4 + 255) / 256, 256, 0, stream>>>(h2, nW3, nb3, ypx, 4);

    // edge MLP
    mfma_gemm_kernel<2, 0><<<mlp_mt, 256, 0, stream>>>(
        use, 768, eW1hi, eW1lo, eb1, h1, 256, GB, 768, 1, nullptr, nullptr);
    mfma_gemm_kernel<2, 0><<<mlp_mt * 2, 256, 0, stream>>>(
        h1, 256, eW2hi, eW2lo, eb2, h2, 512, GB, 256, 2, nullptr, nullptr);
    outhead_kernel<<<(GB * 2 + 255) / 256, 256, 0, stream>>>(h2, eW3, eb3, ypA, 2);

    loss_kernel<<<(GB + 255) / 256, 256, 0, stream>>>(ypx, ypA, y_x, y_A, out);
}